// Round 15
// baseline (88.438 us; speedup 1.0000x reference)
//
#include <hip/hip_runtime.h>
#include <hip/hip_bf16.h>
#include <math.h>

typedef __bf16 bf16;
typedef __bf16 bf16x8 __attribute__((ext_vector_type(8)));
typedef float  f32x4  __attribute__((ext_vector_type(4)));

#define NTOK   16384
#define DIN    512
#define DOUT   512
#define NTYPES 128
#define TEBD   128
#define NEXP   8
#define NPAIR  64      // pair key = e0*8+e1 (e0 = top-1, e1 = top-2, always distinct)
#define MAXTILE 192    // sum_l ceil(n_l/128) <= 64 + 16384/128 = 192

// ---- workspace layout (bytes); total ~20.6 MB ----
#define WS_CNTP    0                          // int[64]  per-pair count
#define WS_NTILE   512                        // int[1]
#define WS_TMAP    1024                       // int2[192] (list, r0)
#define WS_RMAP    4096                       // int[192*128] packed row -> token (pads=0)
#define WS_WGT     (WS_RMAP + MAXTILE * 128 * 4)   // float2[192*128]
#define WS_XB      (WS_WGT + MAXTILE * 128 * 8)    // bf16[16384*512] (16 MB)
#define WS_WET     (WS_XB + (size_t)NTOK * DIN * 2)  // bf16[8*512*512] (4 MB)

#define GLOAD_LDS16(g, l)                                                     \
  __builtin_amdgcn_global_load_lds(                                           \
      (const __attribute__((address_space(1))) void*)(g),                     \
      (__attribute__((address_space(3))) void*)(l), 16, 0, 0)

// ==== ONE prep dispatch: WeT^T ∥ x-cvt ∥ input-only place blocks ============
// [0,512):     We[e][k][n] f32 -> WeT[e][n][k] bf16 (64x64 tiles)
// [512,2560):  x f32 -> xb bf16, LINEAR (R8: gather/packing buys nothing)
// [2560,2624): 64 PLACE blocks, each fully input-determined (R13's redundant
//   recompute, extended): every block redundantly computes
//     (a) the routing gemv for all 128 types (deterministic: identical
//         code+inputs => bitwise-identical floats in every block),
//     (b) its own histogram of ALL 16K atypes with a prefix count
//         pre[ty] = #{i < b*256 : atype[i]=ty} (64KB from L2, ~64 iters),
//     (c) the pair scan (ordered sums, no atomics across blocks).
//   Block b then places tokens [b*256,(b+1)*256) into disjoint slices
//   pos0[ty] = base_pair[p_ty] + within-pair-off[ty] + pre[ty].
//   Zero cross-block communication -> the former scan_place dispatch and
//   its launch gap disappear. Place-block 0 writes cnt_pair/tmap/ntile/pads.
__global__ void fused_prep_kernel(const float* __restrict__ x,
                                  const float* __restrict__ We,
                                  const int* __restrict__ atype,
                                  const float* __restrict__ emb,
                                  const float* __restrict__ Wg,
                                  int* __restrict__ cnt_pair,
                                  int* __restrict__ ntile,
                                  int* __restrict__ tmap,
                                  int* __restrict__ row_map,
                                  float* __restrict__ wgt,
                                  bf16* __restrict__ xb,
                                  bf16* __restrict__ WeT) {
  int bx = blockIdx.x;
  int tid = threadIdx.x;
  if (bx < 512) {
    // ---- We transpose+cvt ----
    __shared__ float tle[64][65];
    int e = bx >> 6;
    int rem = bx & 63;
    int kt = (rem >> 3) * 64;
    int nt = (rem & 7) * 64;
    int col = tid & 63;
    int rq = tid >> 6;
#pragma unroll
    for (int r = 0; r < 16; ++r) {
      int row = rq * 16 + r;
      tle[row][col] = We[((size_t)e * DIN + kt + row) * DOUT + nt + col];
    }
    __syncthreads();
#pragma unroll
    for (int r = 0; r < 16; ++r) {
      int n = rq * 16 + r;
      WeT[((size_t)e * DOUT + nt + n) * DIN + kt + col] = (bf16)tle[col][n];
    }
  } else if (bx < 2560) {
    // ---- x f32 -> xb bf16: 2048 blocks x 256 thr x 16 f32 ----
    size_t base = (size_t)(bx - 512) * 4096 + tid * 16;
    const float4* p = (const float4*)(x + base);
    float4 a0 = p[0], a1 = p[1], a2 = p[2], a3 = p[3];
    bf16x8 o0, o1;
    o0[0] = (bf16)a0.x; o0[1] = (bf16)a0.y; o0[2] = (bf16)a0.z; o0[3] = (bf16)a0.w;
    o0[4] = (bf16)a1.x; o0[5] = (bf16)a1.y; o0[6] = (bf16)a1.z; o0[7] = (bf16)a1.w;
    o1[0] = (bf16)a2.x; o1[1] = (bf16)a2.y; o1[2] = (bf16)a2.z; o1[3] = (bf16)a2.w;
    o1[4] = (bf16)a3.x; o1[5] = (bf16)a3.y; o1[6] = (bf16)a3.z; o1[7] = (bf16)a3.w;
    *(bf16x8*)(xb + base) = o0;
    *(bf16x8*)(xb + base + 8) = o1;
  } else {
    // ---- place block b: tokens [b*256, b*256+256) ----
    __shared__ float s_w0[NTYPES], s_w1[NTYPES];
    __shared__ int s_pair[NTYPES];
    __shared__ int s_pre[NTYPES], s_tot[NTYPES];
    __shared__ int s_cnt[NPAIR], s_base[NPAIR];
    __shared__ int s_pos0[NTYPES];
    __shared__ int lc[NTYPES];
    int b = bx - 2560;

    if (tid < NTYPES) {
      // (a) routing gemv + top-2 softmax for type tid (redundant, determ.)
      const float* er = emb + (size_t)tid * TEBD;
      float lg[NEXP];
#pragma unroll
      for (int e = 0; e < NEXP; ++e) lg[e] = 0.f;
      for (int j = 0; j < TEBD; ++j) {
        float ev = er[j];
#pragma unroll
        for (int e = 0; e < NEXP; ++e) lg[e] += ev * Wg[j * NEXP + e];
      }
      float v0 = -__builtin_inff(), v1 = -__builtin_inff();
      int i0 = 0, i1 = 0;
#pragma unroll
      for (int e = 0; e < NEXP; ++e) {
        float v = lg[e];
        if (v > v0) { v1 = v0; i1 = i0; v0 = v; i0 = e; }
        else if (v > v1) { v1 = v; i1 = e; }
      }
      float d = expf(v1 - v0);
      float inv = 1.f / (1.f + d);
      s_w0[tid] = inv;
      s_w1[tid] = d * inv;
      s_pair[tid] = i0 * 8 + i1;
      s_pre[tid] = 0; s_tot[tid] = 0; lc[tid] = 0;
    }
    __syncthreads();

    // (b) full histogram + prefix-before-this-block (coalesced, 64 iters)
    int lim = b * 256;
    for (int i = tid; i < NTOK; i += 256) {
      int ty = atype[i];
      atomicAdd(&s_tot[ty], 1);
      if (i < lim) atomicAdd(&s_pre[ty], 1);
    }
    __syncthreads();

    // (c) pair totals + 128-aligned scan (ordered, deterministic)
    if (tid < NPAIR) {
      int c = 0;
      for (int t = 0; t < NTYPES; ++t)
        if (s_pair[t] == tid) c += s_tot[t];
      s_cnt[tid] = c;
    }
    __syncthreads();
    if (tid < NPAIR) {
      int bb = 0, tb = 0;
      for (int j = 0; j < tid; ++j) {
        int nt_j = (s_cnt[j] + 127) >> 7;
        bb += nt_j << 7;
        tb += nt_j;
      }
      s_base[tid] = bb;
      if (b == 0) {
        cnt_pair[tid] = s_cnt[tid];
        int nt_l = (s_cnt[tid] + 127) >> 7;
        for (int i = 0; i < nt_l; ++i) {
          tmap[(tb + i) * 2 + 0] = tid;
          tmap[(tb + i) * 2 + 1] = i * 128;
        }
        // pad rows -> token 0 (valid data; masked by nrow in GEMM epilogue)
        for (int i = s_cnt[tid]; i < (nt_l << 7); ++i) row_map[bb + i] = 0;
        if (tid == NPAIR - 1) ntile[0] = tb + nt_l;
      }
    }
    __syncthreads();
    if (tid < NTYPES) {
      int p = s_pair[tid];
      int off = 0;
      for (int t = 0; t < tid; ++t)
        if (s_pair[t] == p) off += s_tot[t];
      s_pos0[tid] = s_base[p] + off + s_pre[tid];
    }
    __syncthreads();

    // place this block's 256 tokens into its disjoint per-type slices
    int t = b * 256 + tid;
    int ty = atype[t];
    int r = atomicAdd(&lc[ty], 1);  // within-block rank (order irrelevant)
    int pos = s_pos0[ty] + r;
    row_map[pos] = t;
    float2 ww; ww.x = s_w0[ty]; ww.y = s_w1[ty];
    ((float2*)wgt)[pos] = ww;
  }
}

// --------- pair-merged grouped GEMM (R12's measured-best, UNCHANGED) -------
// tile: BM=128 x BN=64 x 2 experts, BK=32, 4 waves (2x2), 16x16x32 MFMA.
// DEPTH-4 pipeline: 4 LDS buffers, stage 3 ahead, steady vmcnt(8).
// A rows staged from linear xb via tokS (scattered 64B/row segments).
// LDS 64KB -> 2 blocks/CU. Invariant ~47-48us across every schedule/tile/
// staging variant tried (R1-R14; R10 f32-LDS and R14 reg-staged-A both
// regressed -> bf16 xb + gload_lds is the proven floor). Left untouched.
__global__ __launch_bounds__(256, 2) void moe_gemm_pair_kernel(
    const bf16* __restrict__ xb, const bf16* __restrict__ WeT,
    const float* __restrict__ be, const int* __restrict__ cnt_pair,
    const int* __restrict__ ntile, const int* __restrict__ tmap,
    const int* __restrict__ row_map, const float* __restrict__ wgt,
    float* __restrict__ out) {
  int nwork = ntile[0] * 8;
  int f = blockIdx.y * 8 + blockIdx.x;
  if (f >= nwork) return;
  // bijective chunked XCD swizzle: 8 col-blocks of a row-tile stay on one
  // XCD so the scattered A rows are fetched once and L2-hit 7 times.
  int q = nwork >> 3, r = nwork & 7;
  int xcd = f & 7, idx = f >> 3;
  int L = (xcd < r ? xcd * (q + 1) : r * (q + 1) + (xcd - r) * q) + idx;
  int ti = L >> 3;
  int cx = L & 7;
  int list = tmap[ti * 2 + 0];
  int r0   = tmap[ti * 2 + 1];
  int e0 = list >> 3, e1 = list & 7;
  int nrow = cnt_pair[list] - r0;
  if (nrow > 128) nrow = 128;
  int c0 = cx * 64;
  int arow0 = ti * 128;     // pair bases are 128-aligned

  __shared__ __align__(16) bf16 As[4][128 * 32];
  __shared__ __align__(16) bf16 B0s[4][64 * 32];
  __shared__ __align__(16) bf16 B1s[4][64 * 32];
  __shared__ int   tokS[128];
  __shared__ float w0S[128], w1S[128];
  __shared__ float be0S[64], be1S[64];

  int tid = threadIdx.x;
  int lane = tid & 63, w = tid >> 6;

  // token list / weights / bias first (A staging needs tokS)
  if (tid < 128) {
    int srow = (tid < nrow) ? tid : (nrow - 1);
    tokS[tid] = row_map[arow0 + srow];
    float2 ww = ((const float2*)wgt)[arow0 + srow];
    w0S[tid] = ww.x;
    w1S[tid] = ww.y;
    if (tid < 64) {
      be0S[tid] = be[e0 * DOUT + c0 + tid];
      be1S[tid] = be[e1 * DOUT + c0 + tid];
    }
  }
  __syncthreads();

  // per-lane global sources; chunk swizzle c = cs ^ ((row>>1)&3) keeps the
  // ds_read_b128 side bank-balanced while gload_lds dest stays linear
  const bf16* srcA[2];
#pragma unroll
  for (int j = 0; j < 2; ++j) {
    int slot = w * 128 + j * 64 + lane;
    int row = slot >> 2, cs = slot & 3;
    int c = cs ^ ((row >> 1) & 3);
    srcA[j] = xb + (size_t)tokS[row] * DIN + c * 8;
  }
  const bf16* srcB0;
  const bf16* srcB1;
  {
    int slot = w * 64 + lane;
    int row = slot >> 2, cs = slot & 3;
    int c = cs ^ ((row >> 1) & 3);
    srcB0 = WeT + ((size_t)e0 * DOUT + c0 + row) * DIN + c * 8;
    srcB1 = WeT + ((size_t)e1 * DOUT + c0 + row) * DIN + c * 8;
  }

  auto stage = [&](int buf) {  // 4 gload_lds per wave, then advance one BK
#pragma unroll
    for (int j = 0; j < 2; ++j) {
      GLOAD_LDS16(srcA[j], &As[buf][(w * 128 + j * 64) * 8]);
      srcA[j] += 32;
    }
    GLOAD_LDS16(srcB0, &B0s[buf][w * 64 * 8]);
    GLOAD_LDS16(srcB1, &B1s[buf][w * 64 * 8]);
    srcB0 += 32;
    srcB1 += 32;
  };

  // prologue: 3 tiles in flight (12 loads/wave)
  stage(0);
  stage(1);
  stage(2);

  f32x4 acc0[4][2], acc1[4][2];
#pragma unroll
  for (int mi = 0; mi < 4; ++mi)
#pragma unroll
    for (int ni = 0; ni < 2; ++ni) { acc0[mi][ni] = (f32x4)0.f; acc1[mi][ni] = (f32x4)0.f; }

  int wm = (w >> 1) * 64;
  int wn = (w & 1) * 32;
  int r16 = lane & 15, g16 = lane >> 4;

  int offA[4], offB[2];
#pragma unroll
  for (int i = 0; i < 4; ++i) {
    int rA = wm + i * 16 + r16;
    offA[i] = rA * 32 + (g16 ^ ((rA >> 1) & 3)) * 8;
  }
#pragma unroll
  for (int i = 0; i < 2; ++i) {
    int rB = wn + i * 16 + r16;
    offB[i] = rB * 32 + (g16 ^ ((rB >> 1) & 3)) * 8;
  }

#pragma unroll
  for (int t = 0; t < 16; ++t) {
    // wait for tile t only; tiles t+1..t+3 stay in flight.
    if (t < 14)      asm volatile("s_waitcnt vmcnt(8)" ::: "memory");
    else if (t == 14) asm volatile("s_waitcnt vmcnt(4)" ::: "memory");
    else              asm volatile("s_waitcnt vmcnt(0)" ::: "memory");
    __builtin_amdgcn_s_barrier();
    // overwrite buf[(t+3)&3] == buf[(t-1)&3]: all waves passed the barrier,
    // hence finished their iter t-1 ds_reads (MFMA consumed them)
    if (t + 3 < 16) stage((t + 3) & 3);

    int cur = t & 3;
    bf16x8 af[4], b0f[2], b1f[2];
#pragma unroll
    for (int i = 0; i < 4; ++i) af[i] = *(const bf16x8*)&As[cur][offA[i]];
#pragma unroll
    for (int i = 0; i < 2; ++i) b0f[i] = *(const bf16x8*)&B0s[cur][offB[i]];
#pragma unroll
    for (int i = 0; i < 2; ++i) b1f[i] = *(const bf16x8*)&B1s[cur][offB[i]];
    __builtin_amdgcn_s_setprio(1);
#pragma unroll
    for (int mi = 0; mi < 4; ++mi)
#pragma unroll
      for (int ni = 0; ni < 2; ++ni) {
        acc0[mi][ni] = __builtin_amdgcn_mfma_f32_16x16x32_bf16(
            af[mi], b0f[ni], acc0[mi][ni], 0, 0, 0);
        acc1[mi][ni] = __builtin_amdgcn_mfma_f32_16x16x32_bf16(
            af[mi], b1f[ni], acc1[mi][ni], 0, 0, 0);
      }
    __builtin_amdgcn_s_setprio(0);
  }

  // ---- epilogue: out = w0*tanh(acc0+b0) + w1*tanh(acc1+b1), plain store ---
  // fast tanh: tanh(x) = (e^2x - 1)/(e^2x + 1); clamp |x|<=9, one shared rcp
  // per pair; |err| ~1e-6 << bf16-quant absmax 9.8e-3.
#pragma unroll
  for (int mi = 0; mi < 4; ++mi) {
#pragma unroll
    for (int ni = 0; ni < 2; ++ni) {
      f32x4 v0 = acc0[mi][ni];
      f32x4 v1 = acc1[mi][ni];
      int colLocal = wn + ni * 16 + r16;
      float bev0 = be0S[colLocal];
      float bev1 = be1S[colLocal];
#pragma unroll
      for (int r = 0; r < 4; ++r) {
        int lrow = wm + mi * 16 + g16 * 4 + r;
        if (lrow < nrow) {
          float x0 = fminf(9.f, fmaxf(-9.f, v0[r] + bev0)) * 2.885390082f;
          float x1 = fminf(9.f, fmaxf(-9.f, v1[r] + bev1)) * 2.885390082f;
          float e0v, e1v, invd;
          asm("v_exp_f32 %0, %1" : "=v"(e0v) : "v"(x0));  // 2^(2x*log2e)=e^2x
          asm("v_exp_f32 %0, %1" : "=v"(e1v) : "v"(x1));
          float d0 = e0v + 1.f, d1 = e1v + 1.f;
          asm("v_rcp_f32 %0, %1" : "=v"(invd) : "v"(d0 * d1));
          float t0 = (e0v - 1.f) * d1 * invd;
          float t1 = (e1v - 1.f) * d0 * invd;
          out[(size_t)tokS[lrow] * DOUT + c0 + colLocal] =
              t0 * w0S[lrow] + t1 * w1S[lrow];
        }
      }
    }
  }
}

extern "C" void kernel_launch(void* const* d_in, const int* in_sizes, int n_in,
                              void* d_out, int out_size, void* d_ws, size_t ws_size,
                              hipStream_t stream) {
  const float* x    = (const float*)d_in[0];
  const float* emb  = (const float*)d_in[1];
  const int*   aty  = (const int*)d_in[2];
  const float* Wg   = (const float*)d_in[3];
  const float* We   = (const float*)d_in[4];
  const float* be   = (const float*)d_in[5];
  float* out = (float*)d_out;

  char* ws = (char*)d_ws;
  int*   cnt_pair  = (int*)(ws + WS_CNTP);
  int*   ntile     = (int*)(ws + WS_NTILE);
  int*   tmap      = (int*)(ws + WS_TMAP);
  int*   row_map   = (int*)(ws + WS_RMAP);
  float* wgt       = (float*)(ws + WS_WGT);
  bf16*  xb        = (bf16*)(ws + WS_XB);
  bf16*  WeT       = (bf16*)(ws + WS_WET);

  // ONE prep dispatch: WeT^T ∥ x-cvt ∥ 64 input-only place blocks
  fused_prep_kernel<<<2624, 256, 0, stream>>>(x, We, aty, emb, Wg, cnt_pair,
                                              ntile, tmap, row_map, wgt, xb, WeT);
  // every out element written exactly once -> no memset of out needed
  moe_gemm_pair_kernel<<<dim3(8, MAXTILE), 256, 0, stream>>>(
      xb, WeT, be, cnt_pair, ntile, tmap, row_map, wgt, out);
}

// Round 16
// 71.470 us; speedup vs baseline: 1.2374x; 1.2374x over previous
//
#include <hip/hip_runtime.h>
#include <hip/hip_bf16.h>
#include <math.h>

typedef __bf16 bf16;
typedef __bf16 bf16x8 __attribute__((ext_vector_type(8)));
typedef float  f32x4  __attribute__((ext_vector_type(4)));

#define NTOK   16384
#define DIN    512
#define DOUT   512
#define NTYPES 128
#define TEBD   128
#define NEXP   8
#define NPAIR  64      // pair key = e0*8+e1 (e0 = top-1, e1 = top-2, always distinct)
#define MAXTILE 192    // sum_l ceil(n_l/128) <= 64 + 16384/128 = 192

// ---- workspace layout (bytes); total ~20.6 MB ----
#define WS_HPART   0                          // int[128][64] transposed partials (32KB)
#define WS_ROUTE_W 32768                      // float2[128] (w0,w1) per type
#define WS_PAIR    33792                      // int[128] pair per type
#define WS_BASET   34304                      // int[128] packed base per type
#define WS_CURS    34816                      // int[128] per-type cursor
#define WS_CNTP    35328                      // int[64]  per-pair count
#define WS_NTILE   35840                      // int[1]
#define WS_TMAP    36352                      // int2[192] (list, r0)
#define WS_RMAP    38400                      // int[192*128] packed row -> token (pads=0)
#define WS_WGT     (WS_RMAP + MAXTILE * 128 * 4)   // float2[192*128]
#define WS_XB      (WS_WGT + MAXTILE * 128 * 8)    // bf16[16384*512] (16 MB)
#define WS_WET     (WS_XB + (size_t)NTOK * DIN * 2)  // bf16[8*512*512] (4 MB)

#define GLOAD_LDS16(g, l)                                                     \
  __builtin_amdgcn_global_load_lds(                                           \
      (const __attribute__((address_space(1))) void*)(g),                     \
      (__attribute__((address_space(3))) void*)(l), 16, 0, 0)

// ---- fused prep, 4 independent block ranges (all input-only) --------------
// [0,64):     per-block type-hist partials, transposed hpart[type][block]
// 64:         routing gemv: logits = emb @ Wg, top-2, softmax -> route_w, pair
// [65,577):   We[e][k][n] f32 -> WeT[e][n][k] bf16 (64x64 tiles)
// [577,2625): x f32 -> xb bf16, LINEAR (R8: gather/packing buys nothing)
// NOTE (R15 lesson): do NOT append the place blocks here -- blocks dispatch
// in order, so tail blocks serialize AFTER the BW phase instead of
// overlapping it (+16us). The small route_scan/place dispatches are cheaper.
__global__ void fused_prep_kernel(const float* __restrict__ x,
                                  const float* __restrict__ We,
                                  const int* __restrict__ atype,
                                  const float* __restrict__ emb,
                                  const float* __restrict__ Wg,
                                  int* __restrict__ hpart,
                                  float* __restrict__ route_w,
                                  int* __restrict__ pair_ws,
                                  bf16* __restrict__ xb,
                                  bf16* __restrict__ WeT) {
  int bx = blockIdx.x;
  int tid = threadIdx.x;
  if (bx < 64) {
    __shared__ int h[NTYPES];
    if (tid < NTYPES) h[tid] = 0;
    __syncthreads();
    int t = bx * 256 + tid;
    atomicAdd(&h[atype[t]], 1);
    __syncthreads();
    if (tid < NTYPES) hpart[tid * 64 + bx] = h[tid];
  } else if (bx == 64) {
    // ---- routing gemv + top-2 + softmax, 128 active threads ----
    int t = tid;
    if (t >= NTYPES) return;
    const float* er = emb + (size_t)t * TEBD;
    float lg[NEXP];
#pragma unroll
    for (int e = 0; e < NEXP; ++e) lg[e] = 0.f;
    for (int j = 0; j < TEBD; ++j) {
      float ev = er[j];
#pragma unroll
      for (int e = 0; e < NEXP; ++e) lg[e] += ev * Wg[j * NEXP + e];
    }
    float v0 = -__builtin_inff(), v1 = -__builtin_inff();
    int i0 = 0, i1 = 0;
#pragma unroll
    for (int e = 0; e < NEXP; ++e) {
      float v = lg[e];
      if (v > v0) { v1 = v0; i1 = i0; v0 = v; i0 = e; }
      else if (v > v1) { v1 = v; i1 = e; }
    }
    float d = expf(v1 - v0);
    float inv = 1.f / (1.f + d);
    route_w[t * 2 + 0] = inv;
    route_w[t * 2 + 1] = d * inv;
    pair_ws[t] = i0 * 8 + i1;
  } else if (bx < 577) {
    __shared__ float tle[64][65];
    int b2 = bx - 65;         // 512 = 8 experts * 8 * 8 tiles
    int e = b2 >> 6;
    int rem = b2 & 63;
    int kt = (rem >> 3) * 64;
    int nt = (rem & 7) * 64;
    int col = tid & 63;
    int rq = tid >> 6;
#pragma unroll
    for (int r = 0; r < 16; ++r) {
      int row = rq * 16 + r;
      tle[row][col] = We[((size_t)e * DIN + kt + row) * DOUT + nt + col];
    }
    __syncthreads();
#pragma unroll
    for (int r = 0; r < 16; ++r) {
      int n = rq * 16 + r;
      WeT[((size_t)e * DOUT + nt + n) * DIN + kt + col] = (bf16)tle[col][n];
    }
  } else {
    // 2048 blocks x 256 threads x 16 f32 = 8.4M elements
    size_t base = (size_t)(bx - 577) * 4096 + tid * 16;
    const float4* p = (const float4*)(x + base);
    float4 a0 = p[0], a1 = p[1], a2 = p[2], a3 = p[3];
    bf16x8 o0, o1;
    o0[0] = (bf16)a0.x; o0[1] = (bf16)a0.y; o0[2] = (bf16)a0.z; o0[3] = (bf16)a0.w;
    o0[4] = (bf16)a1.x; o0[5] = (bf16)a1.y; o0[6] = (bf16)a1.z; o0[7] = (bf16)a1.w;
    o1[0] = (bf16)a2.x; o1[1] = (bf16)a2.y; o1[2] = (bf16)a2.z; o1[3] = (bf16)a2.w;
    o1[4] = (bf16)a3.x; o1[5] = (bf16)a3.y; o1[6] = (bf16)a3.z; o1[7] = (bf16)a3.w;
    *(bf16x8*)(xb + base) = o0;
    *(bf16x8*)(xb + base + 8) = o1;
  }
}

// ---- route_scan_lite: hist reduce + pair scan + tile map, one block -------
// base_pair is 128-ALIGNED so packed tile ti <-> rows [ti*128, ti*128+128).
// Pad rows get row_map=0 (token 0: valid data, masked by nrow in epilogue).
__global__ void route_scan_kernel(const int* __restrict__ hpart,
                                  const int* __restrict__ pair_ws,
                                  int* __restrict__ base_type,
                                  int* __restrict__ cursor,
                                  int* __restrict__ cnt_pair,
                                  int* __restrict__ ntile,
                                  int* __restrict__ tmap,
                                  int* __restrict__ row_map) {
  __shared__ int s_cnt[NPAIR];
  __shared__ int s_base[NPAIR];
  __shared__ int s_off[NTYPES];
  __shared__ int s_pair[NTYPES];
  int t = threadIdx.x;  // 128 threads = 128 types
  if (t < NPAIR) s_cnt[t] = 0;
  __syncthreads();

  // reduce the 64 per-block hist partials: 16 independent int4 loads
  int myc = 0;
  {
    const int4* hp = (const int4*)(hpart + t * 64);
#pragma unroll
    for (int b = 0; b < 16; ++b) {
      int4 v = hp[b];
      myc += v.x + v.y + v.z + v.w;
    }
  }
  int p = pair_ws[t];
  s_pair[t] = p;
  s_off[t] = atomicAdd(&s_cnt[p], myc);
  cursor[t] = 0;
  __syncthreads();

  if (t < NPAIR) {
    int b = 0, tb = 0;
    for (int j = 0; j < t; ++j) {
      int nt_j = (s_cnt[j] + 127) >> 7;
      b += nt_j << 7;          // 128-aligned cumulative base
      tb += nt_j;
    }
    s_base[t] = b;
    cnt_pair[t] = s_cnt[t];
    int nt_l = (s_cnt[t] + 127) >> 7;
    for (int i = 0; i < nt_l; ++i) {
      tmap[(tb + i) * 2 + 0] = t;
      tmap[(tb + i) * 2 + 1] = i * 128;
    }
    for (int i = s_cnt[t]; i < (nt_l << 7); ++i) row_map[b + i] = 0;
    if (t == NPAIR - 1) ntile[0] = tb + nt_l;
  }
  __syncthreads();
  base_type[t] = s_base[s_pair[t]] + s_off[t];
}

// ------------- place: token -> packed row (row_map, wgt) — indices only ----
__global__ void place_kernel(const int* __restrict__ atype,
                             const float* __restrict__ route_w,
                             const int* __restrict__ base_type,
                             int* __restrict__ cursor,
                             int* __restrict__ row_map,
                             float* __restrict__ wgt) {
  __shared__ int lc[NTYPES];
  __shared__ int lb[NTYPES];
  int tid = threadIdx.x;
  if (tid < NTYPES) lc[tid] = 0;
  __syncthreads();
  int t = blockIdx.x * 256 + tid;
  int ty = atype[t];
  int r = atomicAdd(&lc[ty], 1);
  __syncthreads();
  if (tid < NTYPES) lb[tid] = lc[tid] ? atomicAdd(&cursor[tid], lc[tid]) : 0;
  __syncthreads();
  int pos = base_type[ty] + lb[ty] + r;
  row_map[pos] = t;
  ((float2*)wgt)[pos] = ((const float2*)route_w)[ty];
}

// --------- pair-merged grouped GEMM (measured-best, UNCHANGED) -------------
// tile: BM=128 x BN=64 x 2 experts, BK=32, 4 waves (2x2), 16x16x32 MFMA.
// DEPTH-4 pipeline: 4 LDS buffers, stage 3 ahead, steady vmcnt(8).
// A rows staged from linear xb via tokS (scattered 64B/row segments).
// LDS 64KB -> 2 blocks/CU. Invariant ~47-48us across every schedule/tile/
// staging variant tried (R1-R15) -- structure-latency-bound, left untouched.
__global__ __launch_bounds__(256, 2) void moe_gemm_pair_kernel(
    const bf16* __restrict__ xb, const bf16* __restrict__ WeT,
    const float* __restrict__ be, const int* __restrict__ cnt_pair,
    const int* __restrict__ ntile, const int* __restrict__ tmap,
    const int* __restrict__ row_map, const float* __restrict__ wgt,
    float* __restrict__ out) {
  int nwork = ntile[0] * 8;
  int f = blockIdx.y * 8 + blockIdx.x;
  if (f >= nwork) return;
  // bijective chunked XCD swizzle: 8 col-blocks of a row-tile stay on one
  // XCD so the scattered A rows are fetched once and L2-hit 7 times.
  int q = nwork >> 3, r = nwork & 7;
  int xcd = f & 7, idx = f >> 3;
  int L = (xcd < r ? xcd * (q + 1) : r * (q + 1) + (xcd - r) * q) + idx;
  int ti = L >> 3;
  int cx = L & 7;
  int list = tmap[ti * 2 + 0];
  int r0   = tmap[ti * 2 + 1];
  int e0 = list >> 3, e1 = list & 7;
  int nrow = cnt_pair[list] - r0;
  if (nrow > 128) nrow = 128;
  int c0 = cx * 64;
  int arow0 = ti * 128;     // pair bases are 128-aligned

  __shared__ __align__(16) bf16 As[4][128 * 32];
  __shared__ __align__(16) bf16 B0s[4][64 * 32];
  __shared__ __align__(16) bf16 B1s[4][64 * 32];
  __shared__ int   tokS[128];
  __shared__ float w0S[128], w1S[128];
  __shared__ float be0S[64], be1S[64];

  int tid = threadIdx.x;
  int lane = tid & 63, w = tid >> 6;

  // token list / weights / bias first (A staging needs tokS)
  if (tid < 128) {
    int srow = (tid < nrow) ? tid : (nrow - 1);
    tokS[tid] = row_map[arow0 + srow];
    float2 ww = ((const float2*)wgt)[arow0 + srow];
    w0S[tid] = ww.x;
    w1S[tid] = ww.y;
    if (tid < 64) {
      be0S[tid] = be[e0 * DOUT + c0 + tid];
      be1S[tid] = be[e1 * DOUT + c0 + tid];
    }
  }
  __syncthreads();

  // per-lane global sources; chunk swizzle c = cs ^ ((row>>1)&3) keeps the
  // ds_read_b128 side bank-balanced while gload_lds dest stays linear
  const bf16* srcA[2];
#pragma unroll
  for (int j = 0; j < 2; ++j) {
    int slot = w * 128 + j * 64 + lane;
    int row = slot >> 2, cs = slot & 3;
    int c = cs ^ ((row >> 1) & 3);
    srcA[j] = xb + (size_t)tokS[row] * DIN + c * 8;
  }
  const bf16* srcB0;
  const bf16* srcB1;
  {
    int slot = w * 64 + lane;
    int row = slot >> 2, cs = slot & 3;
    int c = cs ^ ((row >> 1) & 3);
    srcB0 = WeT + ((size_t)e0 * DOUT + c0 + row) * DIN + c * 8;
    srcB1 = WeT + ((size_t)e1 * DOUT + c0 + row) * DIN + c * 8;
  }

  auto stage = [&](int buf) {  // 4 gload_lds per wave, then advance one BK
#pragma unroll
    for (int j = 0; j < 2; ++j) {
      GLOAD_LDS16(srcA[j], &As[buf][(w * 128 + j * 64) * 8]);
      srcA[j] += 32;
    }
    GLOAD_LDS16(srcB0, &B0s[buf][w * 64 * 8]);
    GLOAD_LDS16(srcB1, &B1s[buf][w * 64 * 8]);
    srcB0 += 32;
    srcB1 += 32;
  };

  // prologue: 3 tiles in flight (12 loads/wave)
  stage(0);
  stage(1);
  stage(2);

  f32x4 acc0[4][2], acc1[4][2];
#pragma unroll
  for (int mi = 0; mi < 4; ++mi)
#pragma unroll
    for (int ni = 0; ni < 2; ++ni) { acc0[mi][ni] = (f32x4)0.f; acc1[mi][ni] = (f32x4)0.f; }

  int wm = (w >> 1) * 64;
  int wn = (w & 1) * 32;
  int r16 = lane & 15, g16 = lane >> 4;

  int offA[4], offB[2];
#pragma unroll
  for (int i = 0; i < 4; ++i) {
    int rA = wm + i * 16 + r16;
    offA[i] = rA * 32 + (g16 ^ ((rA >> 1) & 3)) * 8;
  }
#pragma unroll
  for (int i = 0; i < 2; ++i) {
    int rB = wn + i * 16 + r16;
    offB[i] = rB * 32 + (g16 ^ ((rB >> 1) & 3)) * 8;
  }

#pragma unroll
  for (int t = 0; t < 16; ++t) {
    // wait for tile t only; tiles t+1..t+3 stay in flight.
    if (t < 14)      asm volatile("s_waitcnt vmcnt(8)" ::: "memory");
    else if (t == 14) asm volatile("s_waitcnt vmcnt(4)" ::: "memory");
    else              asm volatile("s_waitcnt vmcnt(0)" ::: "memory");
    __builtin_amdgcn_s_barrier();
    // overwrite buf[(t+3)&3] == buf[(t-1)&3]: all waves passed the barrier,
    // hence finished their iter t-1 ds_reads (MFMA consumed them)
    if (t + 3 < 16) stage((t + 3) & 3);

    int cur = t & 3;
    bf16x8 af[4], b0f[2], b1f[2];
#pragma unroll
    for (int i = 0; i < 4; ++i) af[i] = *(const bf16x8*)&As[cur][offA[i]];
#pragma unroll
    for (int i = 0; i < 2; ++i) b0f[i] = *(const bf16x8*)&B0s[cur][offB[i]];
#pragma unroll
    for (int i = 0; i < 2; ++i) b1f[i] = *(const bf16x8*)&B1s[cur][offB[i]];
    __builtin_amdgcn_s_setprio(1);
#pragma unroll
    for (int mi = 0; mi < 4; ++mi)
#pragma unroll
      for (int ni = 0; ni < 2; ++ni) {
        acc0[mi][ni] = __builtin_amdgcn_mfma_f32_16x16x32_bf16(
            af[mi], b0f[ni], acc0[mi][ni], 0, 0, 0);
        acc1[mi][ni] = __builtin_amdgcn_mfma_f32_16x16x32_bf16(
            af[mi], b1f[ni], acc1[mi][ni], 0, 0, 0);
      }
    __builtin_amdgcn_s_setprio(0);
  }

  // ---- epilogue: out = w0*tanh(acc0+b0) + w1*tanh(acc1+b1), plain store ---
  // fast tanh: tanh(x) = (e^2x - 1)/(e^2x + 1); clamp |x|<=9, one shared rcp
  // per pair; |err| ~1e-6 << bf16-quant absmax 9.8e-3.
#pragma unroll
  for (int mi = 0; mi < 4; ++mi) {
#pragma unroll
    for (int ni = 0; ni < 2; ++ni) {
      f32x4 v0 = acc0[mi][ni];
      f32x4 v1 = acc1[mi][ni];
      int colLocal = wn + ni * 16 + r16;
      float bev0 = be0S[colLocal];
      float bev1 = be1S[colLocal];
#pragma unroll
      for (int r = 0; r < 4; ++r) {
        int lrow = wm + mi * 16 + g16 * 4 + r;
        if (lrow < nrow) {
          float x0 = fminf(9.f, fmaxf(-9.f, v0[r] + bev0)) * 2.885390082f;
          float x1 = fminf(9.f, fmaxf(-9.f, v1[r] + bev1)) * 2.885390082f;
          float e0v, e1v, invd;
          asm("v_exp_f32 %0, %1" : "=v"(e0v) : "v"(x0));  // 2^(2x*log2e)=e^2x
          asm("v_exp_f32 %0, %1" : "=v"(e1v) : "v"(x1));
          float d0 = e0v + 1.f, d1 = e1v + 1.f;
          asm("v_rcp_f32 %0, %1" : "=v"(invd) : "v"(d0 * d1));
          float t0 = (e0v - 1.f) * d1 * invd;
          float t1 = (e1v - 1.f) * d0 * invd;
          out[(size_t)tokS[lrow] * DOUT + c0 + colLocal] =
              t0 * w0S[lrow] + t1 * w1S[lrow];
        }
      }
    }
  }
}

extern "C" void kernel_launch(void* const* d_in, const int* in_sizes, int n_in,
                              void* d_out, int out_size, void* d_ws, size_t ws_size,
                              hipStream_t stream) {
  const float* x    = (const float*)d_in[0];
  const float* emb  = (const float*)d_in[1];
  const int*   aty  = (const int*)d_in[2];
  const float* Wg   = (const float*)d_in[3];
  const float* We   = (const float*)d_in[4];
  const float* be   = (const float*)d_in[5];
  float* out = (float*)d_out;

  char* ws = (char*)d_ws;
  int*   hpart     = (int*)(ws + WS_HPART);
  float* route_w   = (float*)(ws + WS_ROUTE_W);
  int*   pair_ws   = (int*)(ws + WS_PAIR);
  int*   base_type = (int*)(ws + WS_BASET);
  int*   cursor    = (int*)(ws + WS_CURS);
  int*   cnt_pair  = (int*)(ws + WS_CNTP);
  int*   ntile     = (int*)(ws + WS_NTILE);
  int*   tmap      = (int*)(ws + WS_TMAP);
  int*   row_map   = (int*)(ws + WS_RMAP);
  float* wgt       = (float*)(ws + WS_WGT);
  bf16*  xb        = (bf16*)(ws + WS_XB);
  bf16*  WeT       = (bf16*)(ws + WS_WET);

  // hist ∥ route-gemv ∥ WeT transpose ∥ linear x->bf16, one dispatch
  fused_prep_kernel<<<2625, 256, 0, stream>>>(x, We, aty, emb, Wg, hpart,
                                              route_w, pair_ws, xb, WeT);
  route_scan_kernel<<<1, 128, 0, stream>>>(hpart, pair_ws, base_type, cursor,
                                           cnt_pair, ntile, tmap, row_map);
  place_kernel<<<64, 256, 0, stream>>>(aty, route_w, base_type, cursor,
                                       row_map, wgt);
  // every out element written exactly once -> no memset of out needed
  moe_gemm_pair_kernel<<<dim3(8, MAXTILE), 256, 0, stream>>>(
      xb, WeT, be, cnt_pair, ntile, tmap, row_map, wgt, out);
}